// Round 1
// baseline (160.307 us; speedup 1.0000x reference)
//
#include <hip/hip_runtime.h>
#include <math.h>

// Problem constants (from reference setup_inputs)
#define B 4
#define DEC 256
#define ENC 256
#define HDIM 512

// 2*log2(e): pre-scale projections so exp2(dp'+ep') == e^{2*(dp+ep+bias)}
#define TANH_SCALE 2.8853900817779268f
#define LOG2E 1.4426950408889634f

__device__ __forceinline__ float fast_exp2(float x) { return __builtin_amdgcn_exp2f(x); }
__device__ __forceinline__ float fast_rcp(float x)  { return __builtin_amdgcn_rcpf(x); }

// ---------------------------------------------------------------------------
// Generic 64x64 fp32 GEMM tile: out[r, m] = (sum_k X[r,k]*W[k,m] + bias[m])*scale
// X row stride == K. W row stride == 512. out row stride == 512.
// block = 256 threads, each computes 4x4. K-chunks of 16 staged in LDS.
// ---------------------------------------------------------------------------
__device__ __forceinline__ void gemm_tile(
    const float* __restrict__ X, const float* __restrict__ W,
    const float* __restrict__ bias, float scale, float* __restrict__ out,
    int K, float (*As)[68], float (*Bs)[68])
{
    const int tid = threadIdx.x;
    const int tx = tid & 15, ty = tid >> 4;
    const int r0 = blockIdx.y * 64, m0 = blockIdx.x * 64;

    const int ra = tid >> 2, ka = (tid & 3) << 2;   // A: 64 rows x 16 k
    const int kb = tid >> 4, mb = (tid & 15) << 2;  // B: 16 k x 64 m

    float acc[4][4] = {};

    for (int k0 = 0; k0 < K; k0 += 16) {
        float4 a4 = *(const float4*)(X + (long)(r0 + ra) * K + k0 + ka);
        float4 b4 = *(const float4*)(W + (long)(k0 + kb) * 512 + m0 + mb);
        As[ka + 0][ra] = a4.x; As[ka + 1][ra] = a4.y;
        As[ka + 2][ra] = a4.z; As[ka + 3][ra] = a4.w;
        *(float4*)&Bs[kb][mb] = b4;
        __syncthreads();
#pragma unroll
        for (int k = 0; k < 16; ++k) {
            float4 av = *(const float4*)&As[k][ty << 2];
            float4 bv = *(const float4*)&Bs[k][tx << 2];
            float a[4] = {av.x, av.y, av.z, av.w};
            float bb[4] = {bv.x, bv.y, bv.z, bv.w};
#pragma unroll
            for (int i = 0; i < 4; ++i)
#pragma unroll
                for (int j = 0; j < 4; ++j)
                    acc[i][j] = fmaf(a[i], bb[j], acc[i][j]);
        }
        __syncthreads();
    }

    float4 bv = make_float4(0.f, 0.f, 0.f, 0.f);
    if (bias) bv = *(const float4*)(bias + m0 + (tx << 2));
#pragma unroll
    for (int i = 0; i < 4; ++i) {
        float4 o;
        o.x = (acc[i][0] + bv.x) * scale;
        o.y = (acc[i][1] + bv.y) * scale;
        o.z = (acc[i][2] + bv.z) * scale;
        o.w = (acc[i][3] + bv.w) * scale;
        *(float4*)(out + (long)(r0 + (ty << 2) + i) * 512 + m0 + (tx << 2)) = o;
    }
}

// Both projections in one launch (grid.z selects). enc uses W_mlp[:H] (no bias),
// dec uses W_mlp[H:] (+ b_mlp). Both outputs pre-scaled by 2*log2(e).
__global__ __launch_bounds__(256) void proj_kernel(
    const float* __restrict__ enc, const float* __restrict__ dec,
    const float* __restrict__ Wmlp, const float* __restrict__ bmlp,
    float* __restrict__ ep, float* __restrict__ dpb)
{
    __shared__ __align__(16) float As[16][68];
    __shared__ __align__(16) float Bs[16][68];
    if (blockIdx.z == 0)
        gemm_tile(enc, Wmlp, nullptr, TANH_SCALE, ep, HDIM, As, Bs);
    else
        gemm_tile(dec, Wmlp + HDIM * HDIM, bmlp, TANH_SCALE, dpb, HDIM, As, Bs);
}

// context[b,d,h] = sum_e attn[b,d,e] * enc[b,e,h]
__global__ __launch_bounds__(256) void context_kernel(
    const float* __restrict__ attn, const float* __restrict__ enc,
    float* __restrict__ ctx)
{
    __shared__ __align__(16) float As[16][68];
    __shared__ __align__(16) float Bs[16][68];
    const int b = blockIdx.z;
    gemm_tile(attn + (long)b * DEC * ENC, enc + (long)b * ENC * HDIM,
              nullptr, 1.0f, ctx + (long)b * DEC * HDIM, ENC, As, Bs);
}

// ---------------------------------------------------------------------------
// attn logits + softmax, fused. Block = 256 threads (thread == e), one block
// per (b, 4 decoder rows). Inner: acc[d] += Wo[m] * rcp(1 + exp2(dp'[d,m]+ep'[e,m]))
// logit = SumWo + b_out - 2*acc  (since tanh = 1 - 2/(1+e^{2x}))
// ---------------------------------------------------------------------------
#define DT 4

__global__ __launch_bounds__(256) void attn_kernel(
    const float* __restrict__ dpb, const float* __restrict__ ep,
    const float* __restrict__ wo, const float* __restrict__ bout,
    const float* __restrict__ enc, const unsigned char* __restrict__ extm,
    float* __restrict__ attn_out)
{
    __shared__ float eps[256 * 33];     // ep chunk [e][m], stride 33 (bank=(e+m)%32)
    __shared__ float dpbs[DT * HDIM];   // dp' rows for this d-tile
    __shared__ float wos[HDIM];
    __shared__ float red[2][4][DT];

    const int tid = threadIdx.x;
    const int b = blockIdx.y;
    const int d0 = blockIdx.x * DT;

    // stage dp' (4 rows) and Wo
    const float* dpbg = dpb + (long)(b * DEC + d0) * HDIM;
    for (int i = tid; i < DT * HDIM / 4; i += 256)
        *(float4*)&dpbs[i * 4] = *(const float4*)&dpbg[i * 4];
    for (int i = tid; i < HDIM / 4; i += 256)
        *(float4*)&wos[i * 4] = *(const float4*)&wo[i * 4];

    float acc[DT] = {0.f, 0.f, 0.f, 0.f};
    float swo = 0.f;

    const float* epb = ep + (long)b * ENC * HDIM;
    const int f4 = (tid & 7) * 4;
    const int ebase = tid >> 3;

    for (int mc = 0; mc < HDIM; mc += 32) {
        // stage ep'[b, :, mc..mc+31]  (256 e x 32 m)
#pragma unroll
        for (int i = 0; i < 8; ++i) {
            int e = ebase + i * 32;
            float4 v = *(const float4*)&epb[(long)e * HDIM + mc + f4];
            float* dst = &eps[e * 33 + f4];
            dst[0] = v.x; dst[1] = v.y; dst[2] = v.z; dst[3] = v.w;
        }
        __syncthreads();
#pragma unroll 8
        for (int m = 0; m < 32; ++m) {
            float w = wos[mc + m];
            swo += w;
            float evv = eps[tid * 33 + m];
#pragma unroll
            for (int dt = 0; dt < DT; ++dt) {
                float x = dpbs[dt * HDIM + mc + m] + evv;   // scaled 2x*log2e
                float ex = fast_exp2(x);                    // e^{2x}
                float r = fast_rcp(ex + 1.0f);              // 1/(1+e^{2x})
                acc[dt] = fmaf(w, r, acc[dt]);
            }
        }
        __syncthreads();
    }

    // logits + masks
    const float b0 = bout[0];
    const float base = swo + b0;
    const int e = tid;
    const bool pad = (enc[(long)(b * ENC + e) * HDIM] == 0.0f);
    float logit[DT];
#pragma unroll
    for (int dt = 0; dt < DT; ++dt) {
        float l = base - 2.0f * acc[dt];
        bool ext = extm[((long)(b * DEC) + d0 + dt) * ENC + e] != 0;
        logit[dt] = (pad || ext) ? -__builtin_inff() : l;
    }

    // softmax over e (256 lanes = 4 waves)
    const int wave = tid >> 6, lane = tid & 63;
#pragma unroll
    for (int dt = 0; dt < DT; ++dt) {
        float m = logit[dt];
#pragma unroll
        for (int off = 32; off >= 1; off >>= 1)
            m = fmaxf(m, __shfl_xor(m, off, 64));
        if (lane == 0) red[0][wave][dt] = m;
    }
    __syncthreads();
    float p[DT];
#pragma unroll
    for (int dt = 0; dt < DT; ++dt) {
        float gm = fmaxf(fmaxf(red[0][0][dt], red[0][1][dt]),
                         fmaxf(red[0][2][dt], red[0][3][dt]));
        p[dt] = fast_exp2((logit[dt] - gm) * LOG2E);
        float s = p[dt];
#pragma unroll
        for (int off = 32; off >= 1; off >>= 1)
            s += __shfl_xor(s, off, 64);
        if (lane == 0) red[1][wave][dt] = s;
    }
    __syncthreads();
#pragma unroll
    for (int dt = 0; dt < DT; ++dt) {
        float gs = red[1][0][dt] + red[1][1][dt] + red[1][2][dt] + red[1][3][dt];
        float inv = fast_rcp(gs);
        attn_out[((long)(b * DEC) + d0 + dt) * ENC + e] = p[dt] * inv;
    }
}

// ---------------------------------------------------------------------------
extern "C" void kernel_launch(void* const* d_in, const int* in_sizes, int n_in,
                              void* d_out, int out_size, void* d_ws, size_t ws_size,
                              hipStream_t stream) {
    const float* dec = (const float*)d_in[0];
    const float* enc = (const float*)d_in[1];
    const unsigned char* extm = (const unsigned char*)d_in[2]; // bool mask (all-false here)
    const float* Wmlp = (const float*)d_in[3];
    const float* bmlp = (const float*)d_in[4];
    const float* Wout = (const float*)d_in[5];
    const float* bout = (const float*)d_in[6];

    float* ctx = (float*)d_out;                       // [B, DEC, H]
    float* attn = ctx + (size_t)B * DEC * HDIM;       // [B, DEC, ENC]

    float* ep = (float*)d_ws;                         // [B*ENC, H] scaled enc-proj
    float* dpb = ep + (size_t)B * ENC * HDIM;         // [B*DEC, H] scaled dec-proj + bias

    // 1) both projections (z=0: enc, z=1: dec), pre-scaled by 2*log2(e)
    proj_kernel<<<dim3(8, 16, 2), 256, 0, stream>>>(enc, dec, Wmlp, bmlp, ep, dpb);
    // 2) fused tanh-MLP logits + masks + softmax
    attn_kernel<<<dim3(DEC / DT, B), 256, 0, stream>>>(dpb, ep, Wout, bout, enc, extm, attn);
    // 3) context = attn @ enc
    context_kernel<<<dim3(8, 4, 4), 256, 0, stream>>>(attn, enc, ctx);
}